// Round 5
// baseline (110.322 us; speedup 1.0000x reference)
//
#include <hip/hip_runtime.h>
#include <hip/hip_bf16.h>
#include <math.h>

typedef __bf16 bf16_t;
typedef __bf16 bf16x8 __attribute__((ext_vector_type(8)));
typedef float f32x4 __attribute__((ext_vector_type(4)));

#define N2 4096
#define NHALF 2048
#define DIM 512
#define TEMP_INV 2.0f   // 1/TEMPERATURE

// ---------------------------------------------------------------------------
// Kernel 1 (fused prep): one wave per row-PAIR (i, i+N). Loads both fp32 rows,
// computes norms + cross-dot, writes both bf16 rows, pos[i]=pos[p] (symmetric),
// diag per row from the bf16-rounded values (matches what the GEMM will sum),
// and zeroes this block's slice of rowsum.
// ---------------------------------------------------------------------------
__global__ __launch_bounds__(256) void k_prep(const float* __restrict__ x,
                                              bf16_t* __restrict__ xn,
                                              float* __restrict__ pos,
                                              float* __restrict__ diag,
                                              float* __restrict__ rowsum) {
    const int pair = blockIdx.x * 4 + (threadIdx.x >> 6);   // 0..2047
    const int lane = threadIdx.x & 63;
    const int rowi = pair;
    const int rowp = pair + NHALF;

    const float4* xi = reinterpret_cast<const float4*>(x + (size_t)rowi * DIM);
    const float4* xp = reinterpret_cast<const float4*>(x + (size_t)rowp * DIM);
    float4 a0 = xi[lane * 2], a1 = xi[lane * 2 + 1];
    float4 b0 = xp[lane * 2], b1 = xp[lane * 2 + 1];

    float ssi = a0.x*a0.x + a0.y*a0.y + a0.z*a0.z + a0.w*a0.w
              + a1.x*a1.x + a1.y*a1.y + a1.z*a1.z + a1.w*a1.w;
    float ssp = b0.x*b0.x + b0.y*b0.y + b0.z*b0.z + b0.w*b0.w
              + b1.x*b1.x + b1.y*b1.y + b1.z*b1.z + b1.w*b1.w;
    float dot = a0.x*b0.x + a0.y*b0.y + a0.z*b0.z + a0.w*b0.w
              + a1.x*b1.x + a1.y*b1.y + a1.z*b1.z + a1.w*b1.w;
#pragma unroll
    for (int off = 32; off; off >>= 1) {
        ssi += __shfl_xor(ssi, off, 64);
        ssp += __shfl_xor(ssp, off, 64);
        dot += __shfl_xor(dot, off, 64);
    }
    const float ni = fmaxf(sqrtf(ssi), 1e-8f);
    const float np = fmaxf(sqrtf(ssp), 1e-8f);
    const float sci = 1.0f / ni, scp = 1.0f / np;

    float va[8] = {a0.x, a0.y, a0.z, a0.w, a1.x, a1.y, a1.z, a1.w};
    float vb[8] = {b0.x, b0.y, b0.z, b0.w, b1.x, b1.y, b1.z, b1.w};
    bf16x8 oi, op;
    float dii = 0.0f, dpp = 0.0f;
#pragma unroll
    for (int t = 0; t < 8; ++t) {
        oi[t] = (bf16_t)(va[t] * sci);
        op[t] = (bf16_t)(vb[t] * scp);
        float fi = (float)oi[t], fp_ = (float)op[t];
        dii += fi * fi;
        dpp += fp_ * fp_;
    }
    *reinterpret_cast<bf16x8*>(xn + (size_t)rowi * DIM + lane * 8) = oi;
    *reinterpret_cast<bf16x8*>(xn + (size_t)rowp * DIM + lane * 8) = op;
#pragma unroll
    for (int off = 32; off; off >>= 1) {
        dii += __shfl_xor(dii, off, 64);
        dpp += __shfl_xor(dpp, off, 64);
    }
    if (lane == 0) {
        const float pv = TEMP_INV * dot * sci * scp;
        pos[rowi] = pv;
        pos[rowp] = pv;          // sim is symmetric: pos[i] == pos[i+N]
        diag[rowi] = TEMP_INV * dii;
        diag[rowp] = TEMP_INV * dpp;
    }
    // zero rowsum (8 entries per block covers 4096 over 512 blocks)
    if (threadIdx.x < 8) rowsum[blockIdx.x * 8 + threadIdx.x] = 0.0f;
}

// ---------------------------------------------------------------------------
// Kernel 2: symmetric sim-GEMM, upper-triangle blocks only (528 of 1024).
// 128x128 tile, 4 waves 2x2, mfma 16x16x32 bf16.
//
// NO-LDS fragment-direct K-loop (Common-mistake #7 / m169 precedent):
// xn is 4 MB — it fits in each XCD's 4 MB L2. All the staging machinery
// (global_load_lds, double/triple buffers, barriers, counted vmcnt, swizzle)
// existed to feed LDS with data the cache already serves. Drop it: each wave
// loads its MFMA fragments DIRECTLY from global (L2-hot). Fragment row
// {bm,bn}*128 + w*64 + f*16 + l15, k-slice q*8 + kt*32 — per-lane
// global_load_dwordx4; the 16 K-steps fold into offset:kt*64 immediates off
// 8 base addresses computed once (13-bit signed imm, max 960 bytes: fits).
// Per-lane fragment values are bit-identical to the LDS path -> same math.
// Zero barriers in the K-loop; full unroll lets the compiler pipeline loads
// across steps; 2 blocks/CU x 4 waves gives TLP on top.
// ---------------------------------------------------------------------------
__global__ __launch_bounds__(256) void k_simgemm(const bf16_t* __restrict__ xn,
                                                 float* __restrict__ rowsum) {
    __shared__ float rpA[128];
    __shared__ float rpB[128];

    // unrank blockIdx.x -> (bm <= bn) upper-triangle pair
    const int t = blockIdx.x;
    int bn = (int)((sqrtf(8.0f * (float)t + 1.0f) - 1.0f) * 0.5f);
    while ((bn * (bn + 1)) / 2 > t) --bn;
    while (((bn + 1) * (bn + 2)) / 2 <= t) ++bn;
    const int bm = t - (bn * (bn + 1)) / 2;
    const bool diagb = (bm == bn);

    const int tid  = threadIdx.x;
    const int lane = tid & 63;
    const int wid  = tid >> 6;
    const int wr   = wid >> 1;
    const int wc   = wid & 1;
    const int q    = lane >> 4;
    const int l15  = lane & 15;

    if (tid < 128) { rpA[tid] = 0.0f; rpB[tid] = 0.0f; }

    // 8 fragment base addresses (per lane), computed once.
    const bf16_t* aP[4];
    const bf16_t* bP[4];
#pragma unroll
    for (int mt = 0; mt < 4; ++mt)
        aP[mt] = xn + (size_t)(bm * 128 + wr * 64 + mt * 16 + l15) * DIM + q * 8;
#pragma unroll
    for (int nt = 0; nt < 4; ++nt)
        bP[nt] = xn + (size_t)(bn * 128 + wc * 64 + nt * 16 + l15) * DIM + q * 8;

    f32x4 acc[4][4] = {};

#pragma unroll
    for (int kt = 0; kt < 16; ++kt) {
        bf16x8 af[4], bv[4];
#pragma unroll
        for (int mt = 0; mt < 4; ++mt)
            af[mt] = *reinterpret_cast<const bf16x8*>(aP[mt] + kt * 32);
#pragma unroll
        for (int nt = 0; nt < 4; ++nt)
            bv[nt] = *reinterpret_cast<const bf16x8*>(bP[nt] + kt * 32);
#pragma unroll
        for (int mt = 0; mt < 4; ++mt)
#pragma unroll
            for (int nt = 0; nt < 4; ++nt)
                acc[mt][nt] = __builtin_amdgcn_mfma_f32_16x16x32_bf16(
                    af[mt], bv[nt], acc[mt][nt], 0, 0, 0);
    }

    __syncthreads();   // rpA/rpB zero-init visible before epilogue atomics

    // Epilogue. C/D: row = wr*64+mt*16+q*4+r, col = wc*64+nt*16+l15.
    float colacc[4] = {0.0f, 0.0f, 0.0f, 0.0f};
#pragma unroll
    for (int mt = 0; mt < 4; ++mt) {
        float rowp[4] = {0.0f, 0.0f, 0.0f, 0.0f};
#pragma unroll
        for (int nt = 0; nt < 4; ++nt)
#pragma unroll
            for (int r = 0; r < 4; ++r) {
                float e = __expf(TEMP_INV * acc[mt][nt][r]);
                rowp[r] += e;
                colacc[nt] += e;
            }
#pragma unroll
        for (int r = 0; r < 4; ++r) {
            float p = rowp[r];
            p += __shfl_xor(p, 1, 64);
            p += __shfl_xor(p, 2, 64);
            p += __shfl_xor(p, 4, 64);
            p += __shfl_xor(p, 8, 64);
            if (l15 == 0) atomicAdd(&rpA[wr * 64 + mt * 16 + q * 4 + r], p);
        }
    }
    if (!diagb) {
#pragma unroll
        for (int nt = 0; nt < 4; ++nt) {
            float c = colacc[nt];
            c += __shfl_xor(c, 16, 64);
            c += __shfl_xor(c, 32, 64);
            if (q == 0) atomicAdd(&rpB[wc * 64 + nt * 16 + l15], c);
        }
    }
    __syncthreads();
    if (tid < 128) {
        atomicAdd(&rowsum[bm * 128 + tid], rpA[tid]);
    } else if (!diagb) {
        atomicAdd(&rowsum[bn * 128 + (tid - 128)], rpB[tid - 128]);
    }
}

// ---------------------------------------------------------------------------
// Kernel 3: loss = mean_i( log(S_i - exp(diag_i)) - pos_i )
// float4-vectorized single block (4 unrolled rounds of 3x16B loads).
// ---------------------------------------------------------------------------
__global__ __launch_bounds__(256) void k_finalize(const float* __restrict__ rowsum,
                                                  const float* __restrict__ pos,
                                                  const float* __restrict__ diag,
                                                  float* __restrict__ out) {
    __shared__ float red[256];
    const float4* rs4 = reinterpret_cast<const float4*>(rowsum);
    const float4* ps4 = reinterpret_cast<const float4*>(pos);
    const float4* dg4 = reinterpret_cast<const float4*>(diag);
    float s = 0.0f;
#pragma unroll
    for (int it = 0; it < 4; ++it) {
        const int i = it * 256 + threadIdx.x;   // 1024 float4 = 4096 floats
        float4 r = rs4[i];
        float4 p = ps4[i];
        float4 d = dg4[i];
        s += __logf(r.x - __expf(d.x)) - p.x;
        s += __logf(r.y - __expf(d.y)) - p.y;
        s += __logf(r.z - __expf(d.z)) - p.z;
        s += __logf(r.w - __expf(d.w)) - p.w;
    }
    red[threadIdx.x] = s;
    __syncthreads();
    for (int st = 128; st; st >>= 1) {
        if (threadIdx.x < st) red[threadIdx.x] += red[threadIdx.x + st];
        __syncthreads();
    }
    if (threadIdx.x == 0) out[0] = red[0] / (float)N2;
}

// ---------------------------------------------------------------------------
extern "C" void kernel_launch(void* const* d_in, const int* in_sizes, int n_in,
                              void* d_out, int out_size, void* d_ws, size_t ws_size,
                              hipStream_t stream) {
    (void)in_sizes; (void)n_in; (void)out_size; (void)ws_size;
    const float* x = (const float*)d_in[0];
    float* out = (float*)d_out;

    char* ws = (char*)d_ws;
    bf16_t* xn     = (bf16_t*)ws;                          // 4 MB
    float*  rowsum = (float*)(ws + (size_t)N2 * DIM * 2);  // 16 KB
    float*  pos    = rowsum + N2;
    float*  diag   = pos + N2;

    k_prep<<<512, 256, 0, stream>>>(x, xn, pos, diag, rowsum);
    k_simgemm<<<528, 256, 0, stream>>>(xn, rowsum);
    k_finalize<<<1, 256, 0, stream>>>(rowsum, pos, diag, out);
}

// Round 6
// 80.378 us; speedup vs baseline: 1.3725x; 1.3725x over previous
//
#include <hip/hip_runtime.h>
#include <hip/hip_bf16.h>
#include <math.h>

typedef __bf16 bf16_t;
typedef __bf16 bf16x8 __attribute__((ext_vector_type(8)));
typedef float f32x4 __attribute__((ext_vector_type(4)));

#define N2 4096
#define NHALF 2048
#define DIM 512
#define TEMP_INV 2.0f   // 1/TEMPERATURE

// ---------------------------------------------------------------------------
// Kernel 1 (fused prep): one wave per row-PAIR (i, i+N). Loads both fp32 rows,
// computes norms + cross-dot, writes both bf16 rows, pos[i]=pos[p] (symmetric),
// diag per row from the bf16-rounded values (matches what the GEMM will sum),
// and zeroes this block's slice of rowsum.
// ---------------------------------------------------------------------------
__global__ __launch_bounds__(256) void k_prep(const float* __restrict__ x,
                                              bf16_t* __restrict__ xn,
                                              float* __restrict__ pos,
                                              float* __restrict__ diag,
                                              float* __restrict__ rowsum) {
    const int pair = blockIdx.x * 4 + (threadIdx.x >> 6);   // 0..2047
    const int lane = threadIdx.x & 63;
    const int rowi = pair;
    const int rowp = pair + NHALF;

    const float4* xi = reinterpret_cast<const float4*>(x + (size_t)rowi * DIM);
    const float4* xp = reinterpret_cast<const float4*>(x + (size_t)rowp * DIM);
    float4 a0 = xi[lane * 2], a1 = xi[lane * 2 + 1];
    float4 b0 = xp[lane * 2], b1 = xp[lane * 2 + 1];

    float ssi = a0.x*a0.x + a0.y*a0.y + a0.z*a0.z + a0.w*a0.w
              + a1.x*a1.x + a1.y*a1.y + a1.z*a1.z + a1.w*a1.w;
    float ssp = b0.x*b0.x + b0.y*b0.y + b0.z*b0.z + b0.w*b0.w
              + b1.x*b1.x + b1.y*b1.y + b1.z*b1.z + b1.w*b1.w;
    float dot = a0.x*b0.x + a0.y*b0.y + a0.z*b0.z + a0.w*b0.w
              + a1.x*b1.x + a1.y*b1.y + a1.z*b1.z + a1.w*b1.w;
#pragma unroll
    for (int off = 32; off; off >>= 1) {
        ssi += __shfl_xor(ssi, off, 64);
        ssp += __shfl_xor(ssp, off, 64);
        dot += __shfl_xor(dot, off, 64);
    }
    const float ni = fmaxf(sqrtf(ssi), 1e-8f);
    const float np = fmaxf(sqrtf(ssp), 1e-8f);
    const float sci = 1.0f / ni, scp = 1.0f / np;

    float va[8] = {a0.x, a0.y, a0.z, a0.w, a1.x, a1.y, a1.z, a1.w};
    float vb[8] = {b0.x, b0.y, b0.z, b0.w, b1.x, b1.y, b1.z, b1.w};
    bf16x8 oi, op;
    float dii = 0.0f, dpp = 0.0f;
#pragma unroll
    for (int t = 0; t < 8; ++t) {
        oi[t] = (bf16_t)(va[t] * sci);
        op[t] = (bf16_t)(vb[t] * scp);
        float fi = (float)oi[t], fp_ = (float)op[t];
        dii += fi * fi;
        dpp += fp_ * fp_;
    }
    *reinterpret_cast<bf16x8*>(xn + (size_t)rowi * DIM + lane * 8) = oi;
    *reinterpret_cast<bf16x8*>(xn + (size_t)rowp * DIM + lane * 8) = op;
#pragma unroll
    for (int off = 32; off; off >>= 1) {
        dii += __shfl_xor(dii, off, 64);
        dpp += __shfl_xor(dpp, off, 64);
    }
    if (lane == 0) {
        const float pv = TEMP_INV * dot * sci * scp;
        pos[rowi] = pv;
        pos[rowp] = pv;          // sim is symmetric: pos[i] == pos[i+N]
        diag[rowi] = TEMP_INV * dii;
        diag[rowp] = TEMP_INV * dpp;
    }
    // zero rowsum (8 entries per block covers 4096 over 512 blocks)
    if (threadIdx.x < 8) rowsum[blockIdx.x * 8 + threadIdx.x] = 0.0f;
}

// ---------------------------------------------------------------------------
// Kernel 2: symmetric sim-GEMM, 256x256 tiles, upper triangle of 16x16 ->
// 136 blocks x 512 threads (8 waves, 2x4; wave-tile 128x64).
//
// Rationale vs the 128^2 version (r4, ~18.5us): r4 was schedule-bound, not
// BW-bound (5x off both the LDS-BW and MFMA floors). 128x64 wave-tile reads
// 12KB LDS per K-step for 32 MFMAs vs 8KB/16 — 1.5x better read/MFMA — and
// halves barrier+staging rounds per output. Cache traffic 270MB -> 70MB.
//
// Same r4-proven machinery scaled up:
//  - XOR swizzle both-sides (rule #21): source slot (t&3)^((t>>3)&3), read
//    slot q^((l15>>1)&3). Invariant under +128-row and +kt*32-col shifts.
//  - tri-buffer (3 x 32KB), counted vmcnt(4) (4 staging loads/tile/thread),
//    one s_barrier per K-step, sched_barrier(0) pin.
// LDS 98KB -> 1 block/CU; VGPR ~220 (acc 8x4 f32x4 = 128) fits 2 waves/SIMD.
// ---------------------------------------------------------------------------
__device__ __forceinline__ void load_lds16(const bf16_t* g, bf16_t* l) {
    __builtin_amdgcn_global_load_lds(
        (const __attribute__((address_space(1))) unsigned int*)g,
        (__attribute__((address_space(3))) unsigned int*)l,
        16, 0, 0);
}

__global__ __launch_bounds__(512) void k_simgemm(const bf16_t* __restrict__ xn,
                                                 float* __restrict__ rowsum) {
    __shared__ bf16_t As[3][256 * 32];   // 3 x 16KB
    __shared__ bf16_t Bs[3][256 * 32];   // 3 x 16KB
    __shared__ float  rpA[256];
    __shared__ float  rpB[256];

    // unrank blockIdx.x -> (bm <= bn) upper-triangle pair, 16x16 panels
    const int t = blockIdx.x;
    int bn = (int)((sqrtf(8.0f * (float)t + 1.0f) - 1.0f) * 0.5f);
    while ((bn * (bn + 1)) / 2 > t) --bn;
    while (((bn + 1) * (bn + 2)) / 2 <= t) ++bn;
    const int bm = t - (bn * (bn + 1)) / 2;
    const bool diagb = (bm == bn);

    const int tid  = threadIdx.x;
    const int lane = tid & 63;
    const int wid  = tid >> 6;     // 0..7
    const int wr   = wid >> 2;     // 0..1  (M half: 128 rows)
    const int wc   = wid & 3;      // 0..3  (N quarter: 64 cols)
    const int q    = lane >> 4;
    const int l15  = lane & 15;

    if (tid < 256) { rpA[tid] = 0.0f; rpB[tid] = 0.0f; }

    // Staging: one K-tile per matrix = 256 rows x 32 cols bf16 = 16KB =
    // 2 x (512 thr x 16B). thread t covers rows (t>>2) and 128+(t>>2);
    // global slot within the row's 64B window XOR-swizzled; LDS dest linear.
    const int slot_g = (tid & 3) ^ ((tid >> 3) & 3);
    const bf16_t* gA = xn + (size_t)(bm * 256 + (tid >> 2)) * DIM + slot_g * 8;
    const bf16_t* gB = xn + (size_t)(bn * 256 + (tid >> 2)) * DIM + slot_g * 8;

    // fragment-read swizzle: slot_r = q ^ ((row>>1)&3); row = base16 + l15
    // with base16 % 16 == 0 -> (row>>1)&3 == (l15>>1)&3.
    const int rsw  = (q ^ ((l15 >> 1) & 3)) * 8;
    const int arow = (wr * 128 + l15) * 32 + rsw;   // + mt*512
    const int brow = (wc * 64 + l15) * 32 + rsw;    // + nt*512

    f32x4 acc[8][4] = {};

    // prologue: stage K-tiles 0 and 1
#pragma unroll
    for (int p = 0; p < 2; ++p) {
        load_lds16(gA + p * 32,                     &As[p][tid * 8]);
        load_lds16(gA + (size_t)128 * DIM + p * 32, &As[p][4096 + tid * 8]);
        load_lds16(gB + p * 32,                     &Bs[p][tid * 8]);
        load_lds16(gB + (size_t)128 * DIM + p * 32, &Bs[p][4096 + tid * 8]);
    }

#pragma unroll
    for (int kt = 0; kt < 16; ++kt) {
        // confirm tile kt resident (own 4 loads), leave tile kt+1's in flight
        if (kt < 15) asm volatile("s_waitcnt vmcnt(4)" ::: "memory");
        else         asm volatile("s_waitcnt vmcnt(0)" ::: "memory");
        __builtin_amdgcn_s_barrier();      // tile kt resident for all waves;
                                           // all waves' kt-1 reads retired
        __builtin_amdgcn_sched_barrier(0); // pin: nothing floats above

        if (kt + 2 < 16) {                 // stage tile kt+2 (2-step cover)
            const int nb = (kt + 2) % 3;   // == (kt-1)%3, safe per barrier
            const bf16_t* gA2 = gA + (kt + 2) * 32;
            const bf16_t* gB2 = gB + (kt + 2) * 32;
            load_lds16(gA2,                     &As[nb][tid * 8]);
            load_lds16(gA2 + (size_t)128 * DIM, &As[nb][4096 + tid * 8]);
            load_lds16(gB2,                     &Bs[nb][tid * 8]);
            load_lds16(gB2 + (size_t)128 * DIM, &Bs[nb][4096 + tid * 8]);
        }

        const int cb = kt % 3;             // compile-time after unroll
        bf16x8 af[8], bv[4];
#pragma unroll
        for (int mt = 0; mt < 8; ++mt)
            af[mt] = *reinterpret_cast<const bf16x8*>(&As[cb][arow + mt * 512]);
#pragma unroll
        for (int nt = 0; nt < 4; ++nt)
            bv[nt] = *reinterpret_cast<const bf16x8*>(&Bs[cb][brow + nt * 512]);
#pragma unroll
        for (int mt = 0; mt < 8; ++mt)
#pragma unroll
            for (int nt = 0; nt < 4; ++nt)
                acc[mt][nt] = __builtin_amdgcn_mfma_f32_16x16x32_bf16(
                    af[mt], bv[nt], acc[mt][nt], 0, 0, 0);
    }

    // Epilogue. C/D: row = wr*128+mt*16+q*4+r, col = wc*64+nt*16+l15.
    float colacc[4] = {0.0f, 0.0f, 0.0f, 0.0f};
#pragma unroll
    for (int mt = 0; mt < 8; ++mt) {
        float rowp[4] = {0.0f, 0.0f, 0.0f, 0.0f};
#pragma unroll
        for (int nt = 0; nt < 4; ++nt)
#pragma unroll
            for (int r = 0; r < 4; ++r) {
                float e = __expf(TEMP_INV * acc[mt][nt][r]);
                rowp[r] += e;
                colacc[nt] += e;
            }
#pragma unroll
        for (int r = 0; r < 4; ++r) {
            float p = rowp[r];
            p += __shfl_xor(p, 1, 64);
            p += __shfl_xor(p, 2, 64);
            p += __shfl_xor(p, 4, 64);
            p += __shfl_xor(p, 8, 64);
            if (l15 == 0) atomicAdd(&rpA[wr * 128 + mt * 16 + q * 4 + r], p);
        }
    }
    if (!diagb) {
#pragma unroll
        for (int nt = 0; nt < 4; ++nt) {
            float c = colacc[nt];
            c += __shfl_xor(c, 16, 64);
            c += __shfl_xor(c, 32, 64);
            if (q == 0) atomicAdd(&rpB[wc * 64 + nt * 16 + l15], c);
        }
    }
    __syncthreads();
    if (tid < 256) {
        atomicAdd(&rowsum[bm * 256 + tid], rpA[tid]);
    } else if (!diagb) {
        atomicAdd(&rowsum[bn * 256 + (tid - 256)], rpB[tid - 256]);
    }
}

// ---------------------------------------------------------------------------
// Kernel 3: loss = mean_i( log(S_i - exp(diag_i)) - pos_i )
// float4-vectorized single block (4 unrolled rounds of 3x16B loads).
// ---------------------------------------------------------------------------
__global__ __launch_bounds__(256) void k_finalize(const float* __restrict__ rowsum,
                                                  const float* __restrict__ pos,
                                                  const float* __restrict__ diag,
                                                  float* __restrict__ out) {
    __shared__ float red[256];
    const float4* rs4 = reinterpret_cast<const float4*>(rowsum);
    const float4* ps4 = reinterpret_cast<const float4*>(pos);
    const float4* dg4 = reinterpret_cast<const float4*>(diag);
    float s = 0.0f;
#pragma unroll
    for (int it = 0; it < 4; ++it) {
        const int i = it * 256 + threadIdx.x;   // 1024 float4 = 4096 floats
        float4 r = rs4[i];
        float4 p = ps4[i];
        float4 d = dg4[i];
        s += __logf(r.x - __expf(d.x)) - p.x;
        s += __logf(r.y - __expf(d.y)) - p.y;
        s += __logf(r.z - __expf(d.z)) - p.z;
        s += __logf(r.w - __expf(d.w)) - p.w;
    }
    red[threadIdx.x] = s;
    __syncthreads();
    for (int st = 128; st; st >>= 1) {
        if (threadIdx.x < st) red[threadIdx.x] += red[threadIdx.x + st];
        __syncthreads();
    }
    if (threadIdx.x == 0) out[0] = red[0] / (float)N2;
}

// ---------------------------------------------------------------------------
extern "C" void kernel_launch(void* const* d_in, const int* in_sizes, int n_in,
                              void* d_out, int out_size, void* d_ws, size_t ws_size,
                              hipStream_t stream) {
    (void)in_sizes; (void)n_in; (void)out_size; (void)ws_size;
    const float* x = (const float*)d_in[0];
    float* out = (float*)d_out;

    char* ws = (char*)d_ws;
    bf16_t* xn     = (bf16_t*)ws;                          // 4 MB
    float*  rowsum = (float*)(ws + (size_t)N2 * DIM * 2);  // 16 KB
    float*  pos    = rowsum + N2;
    float*  diag   = pos + N2;

    k_prep<<<512, 256, 0, stream>>>(x, xn, pos, diag, rowsum);
    k_simgemm<<<136, 512, 0, stream>>>(xn, rowsum);
    k_finalize<<<1, 256, 0, stream>>>(rowsum, pos, diag, out);
}